// Round 13
// baseline (196.658 us; speedup 1.0000x reference)
//
#include <hip/hip_runtime.h>

// Problem constants
#define B_   2
#define N_   2048
#define C_   1024
#define H_   16
#define D_   64
#define BH_  (B_*H_)      // 32
#define NDH  (N_*D_)      // 131072 elems per (b,h) plane
#define M1   (B_*N_)      // 4096 rows

typedef __attribute__((ext_vector_type(4))) float    f32x4;
typedef __attribute__((ext_vector_type(8))) _Float16 f16x8;
typedef __attribute__((ext_vector_type(4))) _Float16 f16x4;
typedef __attribute__((ext_vector_type(2))) __fp16   h16x2;

#define GLOAD_LDS(gp, lp) \
  __builtin_amdgcn_global_load_lds((const __attribute__((address_space(1))) void*)(gp), \
                                   (__attribute__((address_space(3))) void*)(lp), 16, 0, 0)

// ---- merged prep: fp32->fp16 convert of x (blocks 0..4095) +
//      fp32->fp16 transpose of w_qkv/w_proj + amax zero-init (4096..5119) ----
__global__ __launch_bounds__(256) void k_prep(const float* __restrict__ x,
                                              _Float16* __restrict__ xh,
                                              const float* __restrict__ wq,
                                              const float* __restrict__ wp,
                                              _Float16* __restrict__ whT,
                                              _Float16* __restrict__ wpT,
                                              unsigned* __restrict__ amax_u) {
  __shared__ _Float16 t[64][68];
  int bid = blockIdx.x;
  if (bid < 4096) {
    int i = bid * 256 + threadIdx.x;       // n4 = 4096*256 exactly
    float4 v = ((const float4*)x)[i];
    f16x4 o;
    o.x = (_Float16)v.x; o.y = (_Float16)v.y; o.z = (_Float16)v.z; o.w = (_Float16)v.w;
    ((f16x4*)xh)[i] = o;
    return;
  }
  int idx = bid - 4096;
  if (idx == 0 && threadIdx.x < 64) amax_u[threadIdx.x] = 0u;
  const float* in; _Float16* out; int Cc, cx, cy;
  if (idx < 768) { in = wq; out = whT; Cc = 3072; cx = idx % 48; cy = idx / 48; }
  else { idx -= 768; in = wp; out = wpT; Cc = 1024; cx = idx % 16; cy = idx / 16; }
  const int R = 1024;
  int c0 = cx * 64, r0 = cy * 64;
  int tid = threadIdx.x;
  int cq = tid & 15, rq = tid >> 4;
#pragma unroll
  for (int i = 0; i < 4; ++i) {
    int r = rq + i * 16;
    float4 v = *(const float4*)(in + (size_t)(r0 + r) * Cc + c0 + cq * 4);
    t[r][cq*4+0] = (_Float16)v.x;
    t[r][cq*4+1] = (_Float16)v.y;
    t[r][cq*4+2] = (_Float16)v.z;
    t[r][cq*4+3] = (_Float16)v.w;
  }
  __syncthreads();
#pragma unroll
  for (int i = 0; i < 4; ++i) {
    int c = rq + i * 16;
    f16x4 o;
    o.x = t[cq*4+0][c];
    o.y = t[cq*4+1][c];
    o.z = t[cq*4+2][c];
    o.w = t[cq*4+3][c];
    *(f16x4*)(out + (size_t)(c0 + c) * R + r0 + cq * 4) = o;
  }
}

// ---------------- GEMM1: qkv = x @ w_qkv -------------------------------
// R12 rebuild: 128x128 tile, BK=32, 3-buffer depth-2 prefetch. R12's
// occupancy test falsified "more streams" (25% occ, same time) -> the
// ~3.7k-cy step stall is queued-load latency needing >=2 compute phases
// of cover. Steady state: 12 loads in flight (tiles t,t+1,t+2),
// vmcnt(8) waits only tile t. BK=32 swizzle: read chunk
// c=(quad+(row>>1))&3 (2 lanes/bank, free); source inverts it, LDS
// dest linear. LDS 48KB -> 3 blocks/CU, grid 768 = 1.5 rounds.
__global__ __launch_bounds__(256) void k_gemm_qkv(const _Float16* __restrict__ A,
                                                  const _Float16* __restrict__ BT,
                                                  _Float16* __restrict__ qh,
                                                  _Float16* __restrict__ kh,
                                                  _Float16* __restrict__ vh,
                                                  unsigned* __restrict__ amax_u) {
  __shared__ __align__(16) _Float16 As[3][128 * 32];
  __shared__ __align__(16) _Float16 Bs[3][128 * 32];
  const int tid = threadIdx.x, lane = tid & 63, wave = tid >> 6;
  const int wm = wave >> 1, wn = wave & 1;
  const int mcol = lane & 15, quad = lane >> 4;
  const int m0 = blockIdx.x * 128, n0 = blockIdx.y * 128;
  f32x4 acc[4][4] = {};

  auto stage = [&](int buf, int k0) {           // 4 global_load_lds / thread
#pragma unroll
    for (int r = 0; r < 2; ++r) {
      int s = tid + r * 256;                    // LDS slot (16B), linear dest
      int row = s >> 2, kc = ((s & 3) - (row >> 1)) & 3;  // pre-swizzled src
      GLOAD_LDS(A  + (size_t)(m0 + row) * 1024 + k0 + kc * 8, &As[buf][s * 8]);
      GLOAD_LDS(BT + (size_t)(n0 + row) * 1024 + k0 + kc * 8, &Bs[buf][s * 8]);
    }
  };
  auto compute = [&](int buf) {                 // one K=32 step: 16 MFMA
    f16x8 af[4], bf[4];
#pragma unroll
    for (int tm = 0; tm < 4; ++tm) {
      int row = wm * 64 + tm * 16 + mcol;
      af[tm] = *(const f16x8*)&As[buf][(row * 4 + ((quad + (row >> 1)) & 3)) * 8];
    }
#pragma unroll
    for (int tn = 0; tn < 4; ++tn) {
      int row = wn * 64 + tn * 16 + mcol;
      bf[tn] = *(const f16x8*)&Bs[buf][(row * 4 + ((quad + (row >> 1)) & 3)) * 8];
    }
#pragma unroll
    for (int tm = 0; tm < 4; ++tm)
#pragma unroll
      for (int tn = 0; tn < 4; ++tn)
        acc[tm][tn] = __builtin_amdgcn_mfma_f32_16x16x32_f16(af[tm], bf[tn], acc[tm][tn], 0, 0, 0);
  };

  stage(0, 0);
  stage(1, 32);                                 // 8 loads outstanding
  int cur = 0;
#pragma unroll 1
  for (int t = 0; t < 32; ++t) {
    __builtin_amdgcn_s_barrier();               // all waves past compute(t-1)
    if (t + 2 < 32) {
      int nb = cur >= 1 ? cur - 1 : cur + 2;    // (cur+2)%3 == (t-1)%3, free
      stage(nb, (t + 2) * 32);                  // 12 outstanding
      asm volatile("s_waitcnt vmcnt(8)" ::: "memory");  // tile t landed
    } else if (t + 1 < 32) {
      asm volatile("s_waitcnt vmcnt(4)" ::: "memory");
    } else {
      asm volatile("s_waitcnt vmcnt(0)" ::: "memory");
    }
    __builtin_amdgcn_s_barrier();               // block-wide: tile t staged
    __builtin_amdgcn_sched_barrier(0);
    compute(cur);
    cur = cur == 2 ? 0 : cur + 1;
  }

  const int sec = n0 >> 10;
  if (sec < 2) {
    _Float16* dst = sec ? kh : qh;
    float mxv = 0.f;
#pragma unroll
    for (int tm = 0; tm < 4; ++tm)
#pragma unroll
      for (int tn = 0; tn < 4; ++tn) {
        int rowb = m0 + wm * 64 + tm * 16 + quad * 4;
        int col = n0 + wn * 64 + tn * 16 + mcol;
        int cc = col & 1023, h = cc >> 6, d = cc & 63;
        int b = rowb >> 11, n = rowb & 2047;
        f32x4 a = acc[tm][tn];
        mxv = fmaxf(mxv, fmaxf(fmaxf(fabsf(a[0]), fabsf(a[1])),
                               fmaxf(fabsf(a[2]), fabsf(a[3]))));
        f16x4 o;
        o.x = (_Float16)a[0]; o.y = (_Float16)a[1];
        o.z = (_Float16)a[2]; o.w = (_Float16)a[3];
        *(f16x4*)&dst[(size_t)(b * 16 + h) * 131072 + (size_t)(n >> 5) * 2048 + d * 32 + (n & 31)] = o;
      }
#pragma unroll
    for (int off = 32; off; off >>= 1) mxv = fmaxf(mxv, __shfl_xor(mxv, off));
    if (lane == 0) {
      int head = ((n0 & 1023) >> 6) + wn;
      int plane = (m0 >> 11) * 16 + head;
      atomicMax(&amax_u[sec * 32 + plane], __float_as_uint(mxv));
    }
  } else {
    // V: fragment-transposed layout (R9): slab (d>>4)*512, elem
    // ((n>>3)&3)*128 + (d&15)*8 + (n&7).
#pragma unroll
    for (int tm = 0; tm < 4; ++tm)
#pragma unroll
      for (int tn = 0; tn < 4; ++tn) {
        int rowb = m0 + wm * 64 + tm * 16 + quad * 4;
        int col = n0 + wn * 64 + tn * 16 + mcol;
        int cc = col & 1023, h = cc >> 6, d = cc & 63;
        int b = rowb >> 11, n = rowb & 2047;
        f16x4 o;
        o.x = (_Float16)acc[tm][tn][0];
        o.y = (_Float16)acc[tm][tn][1];
        o.z = (_Float16)acc[tm][tn][2];
        o.w = (_Float16)acc[tm][tn][3];
        size_t e = (size_t)(b * 16 + h) * 131072 + (size_t)(n >> 5) * 2048
                 + (d >> 4) * 512 + ((n >> 3) & 3) * 128 + (d & 15) * 8 + (n & 7);
        *(f16x4*)&vh[e] = o;
      }
  }
}

// ---------------- fp8 e4m3 quantize (tiled fp16 in, LDS transpose) -------
// K fragment interior: quad*128 + mcol*8 (R9, conflict-free). q8 unchanged.
__global__ __launch_bounds__(256) void k_quant(const _Float16* __restrict__ qh,
                                               const _Float16* __restrict__ kh,
                                               const float* __restrict__ amax,
                                               char* __restrict__ q8,
                                               char* __restrict__ k8) {
  __shared__ ushort T[32][72];   // 144B rows: 16B-aligned reads
  int blk = blockIdx.x;
  int which = blk >> 11;
  int idx = blk & 2047;
  int bh = idx >> 6, chunk = idx & 63;
  const _Float16* src = (which ? kh : qh) + (size_t)bh * NDH + chunk * 2048;
  float s = 448.f / fmaxf(amax[which * 32 + bh], 1e-12f);
  int t = threadIdx.x;
  f16x8 v = *(const f16x8*)(src + t * 8);
  int d = t >> 2, kk0 = (t & 3) * 8;
#pragma unroll
  for (int j = 0; j < 8; ++j) T[kk0 + j][d] = ((const ushort*)&v)[j];
  __syncthreads();
  int r = t >> 3, d0 = (t & 7) * 8;
  f16x8 row = *(const f16x8*)&T[r][d0];
  float f[8];
#pragma unroll
  for (int j = 0; j < 8; ++j) f[j] = (float)((const _Float16*)&row)[j] * s;
  int lo = 0, hi = 0;
  lo = __builtin_amdgcn_cvt_pk_fp8_f32(f[0], f[1], lo, false);
  lo = __builtin_amdgcn_cvt_pk_fp8_f32(f[2], f[3], lo, true);
  hi = __builtin_amdgcn_cvt_pk_fp8_f32(f[4], f[5], hi, false);
  hi = __builtin_amdgcn_cvt_pk_fp8_f32(f[6], f[7], hi, true);
  int2 o; o.x = lo; o.y = hi;
  if (which == 0) {
    char* dst = q8 + (size_t)bh * NDH + (size_t)(chunk * 32 + r) * 64 + d0;
    *(int2*)dst = o;
  } else {
    int e = (r >> 2) & 1;
    int mc = (r >> 3) * 4 + (r & 3);
    int kb = d0 >> 5, dq = (d0 >> 3) & 3;
    char* dst = k8 + (size_t)bh * NDH + chunk * 2048 + (e * 2 + kb) * 512 + dq * 128 + mc * 8;
    *(int2*)dst = o;
  }
}

// ---------------- flash causal attention (R10/R11 dual q-group) ----------
__global__ __launch_bounds__(256) void k_flash(const char* __restrict__ q8,
                                               const char* __restrict__ k8,
                                               const _Float16* __restrict__ vh,
                                               const float* __restrict__ amax,
                                               _Float16* __restrict__ attn) {
  const int bh = blockIdx.x;
  const int tid = threadIdx.x;
  const int wave = tid >> 6, lane = tid & 63;
  const int mcol = lane & 15, quad = lane >> 4;
  const int pr = blockIdx.y * 4 + wave;       // 0..63
  const int ga = 127 - pr, gb = pr;
  const int ta  = 16 - (pr >> 3);             // A-tile count (block-uniform)
  const int ntb = (pr >> 3) + 1;              // B-tile count (block-uniform)

  __shared__ __align__(16) char     Ks[2][8192];
  __shared__ __align__(16) _Float16 Vs[2][8192];

  float sq = 448.f / fmaxf(amax[bh], 1e-12f);
  float sk = 448.f / fmaxf(amax[32 + bh], 1e-12f);
  const float c2 = (1.f / (sq * sk)) * 0.125f * 1.44269504089f;  // > 0

  const size_t pbase = (size_t)bh * NDH;
  const char* kpl = k8 + pbase;
  const _Float16* vpl = vh + pbase;
  const int qrowA = ga * 16 + mcol, qrowB = gb * 16 + mcol;
  long aqA0, aqA1, aqB0, aqB1;
  { const char* qp = q8 + pbase + (size_t)qrowA * 64;
    aqA0 = *(const long*)(qp + quad * 8); aqA1 = *(const long*)(qp + 32 + quad * 8); }
  { const char* qp = q8 + pbase + (size_t)qrowB * 64;
    aqB0 = *(const long*)(qp + quad * 8); aqB1 = *(const long*)(qp + 32 + quad * 8); }

  f32x4 OA[4] = {}, OB[4] = {};
  float mA = -3e38f, lA = 0.f, mB = -3e38f, lB = 0.f;
  const int b = bh >> 4, h = bh & 15;
  const int kq = quad * 8;
  const int koff = quad * 128 + mcol * 8;     // bytes into K fragment
  const int voff = quad * 128 + mcol * 8;     // elems into V slab

  auto stage = [&](int buf, int t) {          // 6 global_load_lds / thread
    const char* ks = kpl + (size_t)t * 8192;
    const _Float16* vs = vpl + (size_t)t * 8192;
#pragma unroll
    for (int r = 0; r < 2; ++r)
      GLOAD_LDS(ks + (tid + r * 256) * 16, &Ks[buf][(tid + r * 256) * 16]);
#pragma unroll
    for (int r = 0; r < 4; ++r)
      GLOAD_LDS(vs + (tid + r * 256) * 8, &Vs[buf][(tid + r * 256) * 8]);
  };

  auto softmax = [&](f32x4 (&s)[4][2], bool last, int qrow, int n0,
                     float& m_i, float& l_i, f32x4 (&O)[4], f16x8 (&pb)[4]) {
    if (last) {
#pragma unroll
      for (int p = 0; p < 4; ++p)
#pragma unroll
        for (int e = 0; e < 2; ++e)
#pragma unroll
          for (int r = 0; r < 4; ++r) {
            int key = n0 + p * 32 + kq + e * 4 + r;
            s[p][e][r] = (key <= qrow) ? s[p][e][r] : -3e38f;
          }
    }
    float fm[8];
#pragma unroll
    for (int p = 0; p < 4; ++p)
#pragma unroll
      for (int e = 0; e < 2; ++e) {
        f32x4 v = s[p][e];
        fm[p * 2 + e] = fmaxf(fmaxf(v[0], v[1]), fmaxf(v[2], v[3]));
      }
    float mx = fmaxf(fmaxf(fmaxf(fm[0], fm[1]), fmaxf(fm[2], fm[3])),
                     fmaxf(fmaxf(fm[4], fm[5]), fmaxf(fm[6], fm[7])));
    mx = fmaxf(mx, m_i);
    mx = fmaxf(mx, __shfl_xor(mx, 16));
    mx = fmaxf(mx, __shfl_xor(mx, 32));
    float alpha = __builtin_amdgcn_exp2f((m_i - mx) * c2);
    m_i = mx;
    const float nh = -mx * c2;
    float fs[8];
#pragma unroll
    for (int p = 0; p < 4; ++p)
#pragma unroll
      for (int e = 0; e < 2; ++e) {
        float p0 = __builtin_amdgcn_exp2f(fmaf(s[p][e][0], c2, nh));
        float p1 = __builtin_amdgcn_exp2f(fmaf(s[p][e][1], c2, nh));
        float p2 = __builtin_amdgcn_exp2f(fmaf(s[p][e][2], c2, nh));
        float p3 = __builtin_amdgcn_exp2f(fmaf(s[p][e][3], c2, nh));
        s[p][e][0] = p0; s[p][e][1] = p1; s[p][e][2] = p2; s[p][e][3] = p3;
        fs[p * 2 + e] = (p0 + p1) + (p2 + p3);
      }
    float sum = ((fs[0] + fs[1]) + (fs[2] + fs[3])) + ((fs[4] + fs[5]) + (fs[6] + fs[7]));
    sum += __shfl_xor(sum, 16);
    sum += __shfl_xor(sum, 32);
    l_i = l_i * alpha + sum;
#pragma unroll
    for (int dt = 0; dt < 4; ++dt)
#pragma unroll
      for (int r = 0; r < 4; ++r)
        O[dt][r] *= alpha;
#pragma unroll
    for (int p = 0; p < 4; ++p) {
      h16x2* pb2 = (h16x2*)&pb[p];
      pb2[0] = __builtin_amdgcn_cvt_pkrtz(s[p][0][0], s[p][0][1]);
      pb2[1] = __builtin_amdgcn_cvt_pkrtz(s[p][0][2], s[p][0][3]);
      pb2[2] = __builtin_amdgcn_cvt_pkrtz(s[p][1][0], s[p][1][1]);
      pb2[3] = __builtin_amdgcn_cvt_pkrtz(s[p][1][2], s[p][1][3]);
    }
  };

  stage(0, 0);
#pragma unroll 1
  for (int t = 0; t < ta; ++t) {
    const int cur = t & 1;
    __builtin_amdgcn_s_barrier();
    if (t + 1 < ta) {
      stage(cur ^ 1, t + 1);
      asm volatile("s_waitcnt vmcnt(6)" ::: "memory");
    } else {
      asm volatile("s_waitcnt vmcnt(0)" ::: "memory");
    }
    __builtin_amdgcn_s_barrier();
    __builtin_amdgcn_sched_barrier(0);

    const bool doB = (t < ntb);
    const int n0 = t * 128;
    f32x4 sA[4][2], sB[4][2];
#pragma unroll
    for (int p = 0; p < 4; ++p) {
      long kf0 = *(const long*)&Ks[cur][(p * 4 + 0) * 512 + koff];
      long kf1 = *(const long*)&Ks[cur][(p * 4 + 1) * 512 + koff];
      long kf2 = *(const long*)&Ks[cur][(p * 4 + 2) * 512 + koff];
      long kf3 = *(const long*)&Ks[cur][(p * 4 + 3) * 512 + koff];
      f32x4 z = {};
      z = __builtin_amdgcn_mfma_f32_16x16x32_fp8_fp8(kf0, aqA0, z, 0, 0, 0);
      z = __builtin_amdgcn_mfma_f32_16x16x32_fp8_fp8(kf1, aqA1, z, 0, 0, 0);
      sA[p][0] = z;
      z = (f32x4){};
      z = __builtin_amdgcn_mfma_f32_16x16x32_fp8_fp8(kf2, aqA0, z, 0, 0, 0);
      z = __builtin_amdgcn_mfma_f32_16x16x32_fp8_fp8(kf3, aqA1, z, 0, 0, 0);
      sA[p][1] = z;
      if (doB) {
        z = (f32x4){};
        z = __builtin_amdgcn_mfma_f32_16x16x32_fp8_fp8(kf0, aqB0, z, 0, 0, 0);
        z = __builtin_amdgcn_mfma_f32_16x16x32_fp8_fp8(kf1, aqB1, z, 0, 0, 0);
        sB[p][0] = z;
        z = (f32x4){};
        z = __builtin_amdgcn_mfma_f32_16x16x32_fp8_fp8(kf2, aqB0, z, 0, 0, 0);
        z = __builtin_amdgcn_mfma_f32_16x16x32_fp8_fp8(kf3, aqB1, z, 0, 0, 0);
        sB[p][1] = z;
      }
    }
    f16x8 pbA[4], pbB[4];
    softmax(sA, t == ta - 1, qrowA, n0, mA, lA, OA, pbA);
    if (doB) softmax(sB, t == ntb - 1, qrowB, n0, mB, lB, OB, pbB);
#pragma unroll
    for (int p = 0; p < 4; ++p) {
      f16x8 va0 = *(const f16x8*)&Vs[cur][p * 2048 + 0 * 512 + voff];
      f16x8 va1 = *(const f16x8*)&Vs[cur][p * 2048 + 1 * 512 + voff];
      f16x8 va2 = *(const f16x8*)&Vs[cur][p * 2048 + 2 * 512 + voff];
      f16x8 va3 = *(const f16x8*)&Vs[cur][p * 2048 + 3 * 512 + voff];
      OA[0] = __builtin_amdgcn_mfma_f32_16x16x32_f16(va0, pbA[p], OA[0], 0, 0, 0);
      OA[1] = __builtin_amdgcn_mfma_f32_16x16x32_f16(va1, pbA[p], OA[1], 0, 0, 0);
      OA[2] = __builtin_amdgcn_mfma_f32_16x16x32_f16(va2, pbA[p], OA[2], 0, 0, 0);
      OA[3] = __builtin_amdgcn_mfma_f32_16x16x32_f16(va3, pbA[p], OA[3], 0, 0, 0);
      if (doB) {
        OB[0] = __builtin_amdgcn_mfma_f32_16x16x32_f16(va0, pbB[p], OB[0], 0, 0, 0);
        OB[1] = __builtin_amdgcn_mfma_f32_16x16x32_f16(va1, pbB[p], OB[1], 0, 0, 0);
        OB[2] = __builtin_amdgcn_mfma_f32_16x16x32_f16(va2, pbB[p], OB[2], 0, 0, 0);
        OB[3] = __builtin_amdgcn_mfma_f32_16x16x32_f16(va3, pbB[p], OB[3], 0, 0, 0);
      }
    }
  }

  {
    float rl = __builtin_amdgcn_rcpf(lA);
    _Float16* op = attn + ((size_t)b * 2048 + qrowA) * 1024 + h * 64;
#pragma unroll
    for (int dt = 0; dt < 4; ++dt) {
      f16x4 o;
      o.x = (_Float16)(OA[dt][0] * rl);
      o.y = (_Float16)(OA[dt][1] * rl);
      o.z = (_Float16)(OA[dt][2] * rl);
      o.w = (_Float16)(OA[dt][3] * rl);
      *(f16x4*)(op + dt * 16 + quad * 4) = o;
    }
  }
  {
    float rl = __builtin_amdgcn_rcpf(lB);
    _Float16* op = attn + ((size_t)b * 2048 + qrowB) * 1024 + h * 64;
#pragma unroll
    for (int dt = 0; dt < 4; ++dt) {
      f16x4 o;
      o.x = (_Float16)(OB[dt][0] * rl);
      o.y = (_Float16)(OB[dt][1] * rl);
      o.z = (_Float16)(OB[dt][2] * rl);
      o.w = (_Float16)(OB[dt][3] * rl);
      *(f16x4*)(op + dt * 16 + quad * 4) = o;
    }
  }
}

// ---------------- GEMM2: out = attn @ w_proj + b (R10 128^2 config) ------
__global__ __launch_bounds__(256) void k_gemm_out(const _Float16* __restrict__ A,
                                                  const _Float16* __restrict__ BT,
                                                  const float* __restrict__ bias,
                                                  float* __restrict__ out) {
  __shared__ __align__(16) _Float16 As[2][128 * 64];
  __shared__ __align__(16) _Float16 Bs[2][128 * 64];
  const int tid = threadIdx.x, lane = tid & 63, wave = tid >> 6;
  const int wm = wave >> 1, wn = wave & 1;
  const int mcol = lane & 15, quad = lane >> 4;
  const int m0 = blockIdx.x * 128, n0 = blockIdx.y * 128;
  const int swa = mcol & 7;
  f32x4 acc[4][4] = {};

  auto stage = [&](int buf, int k0) {
#pragma unroll
    for (int r = 0; r < 4; ++r) {
      int s = tid + r * 256;
      int row = s >> 3, kc = (s & 7) ^ (row & 7);
      GLOAD_LDS(A  + (size_t)(m0 + row) * 1024 + k0 + kc * 8, &As[buf][s * 8]);
      GLOAD_LDS(BT + (size_t)(n0 + row) * 1024 + k0 + kc * 8, &Bs[buf][s * 8]);
    }
  };
  auto compute = [&](int buf) {
#pragma unroll
    for (int kk = 0; kk < 2; ++kk) {
      f16x8 af[4], bf[4];
#pragma unroll
      for (int tm = 0; tm < 4; ++tm) {
        int row = wm * 64 + tm * 16 + mcol;
        af[tm] = *(const f16x8*)&As[buf][(row * 8 + ((kk * 4 + quad) ^ swa)) * 8];
      }
#pragma unroll
      for (int tn = 0; tn < 4; ++tn) {
        int row = wn * 64 + tn * 16 + mcol;
        bf[tn] = *(const f16x8*)&Bs[buf][(row * 8 + ((kk * 4 + quad) ^ swa)) * 8];
      }
#pragma unroll
      for (int tm = 0; tm < 4; ++tm)
#pragma unroll
        for (int tn = 0; tn < 4; ++tn)
          acc[tm][tn] = __builtin_amdgcn_mfma_f32_16x16x32_f16(af[tm], bf[tn], acc[tm][tn], 0, 0, 0);
    }
  };

  stage(0, 0);
#pragma unroll 1
  for (int t = 0; t < 16; ++t) {
    const int cur = t & 1;
    __builtin_amdgcn_s_barrier();
    if (t + 1 < 16) {
      stage(cur ^ 1, (t + 1) * 64);
      asm volatile("s_waitcnt vmcnt(8)" ::: "memory");
    } else {
      asm volatile("s_waitcnt vmcnt(0)" ::: "memory");
    }
    __builtin_amdgcn_s_barrier();
    __builtin_amdgcn_sched_barrier(0);
    compute(cur);
  }

#pragma unroll
  for (int tm = 0; tm < 4; ++tm)
#pragma unroll
    for (int tn = 0; tn < 4; ++tn)
#pragma unroll
      for (int reg = 0; reg < 4; ++reg) {
        int row = m0 + wm * 64 + tm * 16 + quad * 4 + reg;
        int col = n0 + wn * 64 + tn * 16 + mcol;
        out[(size_t)row * 1024 + col] = acc[tm][tn][reg] + bias[col];
      }
}

extern "C" void kernel_launch(void* const* d_in, const int* in_sizes, int n_in,
                              void* d_out, int out_size, void* d_ws, size_t ws_size,
                              hipStream_t stream) {
  const float* x      = (const float*)d_in[0];
  const float* w_qkv  = (const float*)d_in[1];
  const float* w_proj = (const float*)d_in[2];
  const float* b_proj = (const float*)d_in[3];
  float* out = (float*)d_out;

  char* ws = (char*)d_ws;
  _Float16* xh   = (_Float16*)ws; ws += (size_t)M1 * C_ * 2;
  _Float16* whT  = (_Float16*)ws; ws += (size_t)3 * C_ * C_ * 2;
  _Float16* wpT  = (_Float16*)ws; ws += (size_t)C_ * C_ * 2;
  _Float16* qh   = (_Float16*)ws; ws += (size_t)BH_ * NDH * 2;
  _Float16* kh   = (_Float16*)ws; ws += (size_t)BH_ * NDH * 2;
  _Float16* vh   = (_Float16*)ws; ws += (size_t)BH_ * NDH * 2;
  char*     q8   = (char*)ws;     ws += (size_t)BH_ * NDH;
  char*     k8   = (char*)ws;     ws += (size_t)BH_ * NDH;
  _Float16* attn = (_Float16*)ws; ws += (size_t)M1 * C_ * 2;
  float*    amx  = (float*)ws;    ws += 256;

  k_prep<<<5120, 256, 0, stream>>>(x, xh, w_qkv, w_proj, whT, wpT, (unsigned*)amx);
  k_gemm_qkv<<<dim3(M1 / 128, 3 * C_ / 128), 256, 0, stream>>>(xh, whT, qh, kh, vh, (unsigned*)amx);
  k_quant<<<4096, 256, 0, stream>>>(qh, kh, amx, q8, k8);
  k_flash<<<dim3(32, 16), 256, 0, stream>>>(q8, k8, vh, amx, attn);
  k_gemm_out<<<dim3(M1 / 128, C_ / 128), 256, 0, stream>>>(attn, wpT, b_proj, out);
}

// Round 14
// 184.086 us; speedup vs baseline: 1.0683x; 1.0683x over previous
//
#include <hip/hip_runtime.h>

// Problem constants
#define B_   2
#define N_   2048
#define C_   1024
#define H_   16
#define D_   64
#define BH_  (B_*H_)      // 32
#define NDH  (N_*D_)      // 131072 elems per (b,h) plane
#define M1   (B_*N_)      // 4096 rows

typedef __attribute__((ext_vector_type(4))) float    f32x4;
typedef __attribute__((ext_vector_type(8))) _Float16 f16x8;
typedef __attribute__((ext_vector_type(4))) _Float16 f16x4;
typedef __attribute__((ext_vector_type(2))) __fp16   h16x2;

#define GLOAD_LDS(gp, lp) \
  __builtin_amdgcn_global_load_lds((const __attribute__((address_space(1))) void*)(gp), \
                                   (__attribute__((address_space(3))) void*)(lp), 16, 0, 0)

// ---- merged prep: fp32->fp16 convert of x (blocks 0..4095) +
//      fp32->fp16 transpose of w_qkv/w_proj + amax zero-init (4096..5119) ----
__global__ __launch_bounds__(256) void k_prep(const float* __restrict__ x,
                                              _Float16* __restrict__ xh,
                                              const float* __restrict__ wq,
                                              const float* __restrict__ wp,
                                              _Float16* __restrict__ whT,
                                              _Float16* __restrict__ wpT,
                                              unsigned* __restrict__ amax_u) {
  __shared__ _Float16 t[64][68];
  int bid = blockIdx.x;
  if (bid < 4096) {
    int i = bid * 256 + threadIdx.x;       // n4 = 4096*256 exactly
    float4 v = ((const float4*)x)[i];
    f16x4 o;
    o.x = (_Float16)v.x; o.y = (_Float16)v.y; o.z = (_Float16)v.z; o.w = (_Float16)v.w;
    ((f16x4*)xh)[i] = o;
    return;
  }
  int idx = bid - 4096;
  if (idx == 0 && threadIdx.x < 64) amax_u[threadIdx.x] = 0u;
  const float* in; _Float16* out; int Cc, cx, cy;
  if (idx < 768) { in = wq; out = whT; Cc = 3072; cx = idx % 48; cy = idx / 48; }
  else { idx -= 768; in = wp; out = wpT; Cc = 1024; cx = idx % 16; cy = idx / 16; }
  const int R = 1024;
  int c0 = cx * 64, r0 = cy * 64;
  int tid = threadIdx.x;
  int cq = tid & 15, rq = tid >> 4;
#pragma unroll
  for (int i = 0; i < 4; ++i) {
    int r = rq + i * 16;
    float4 v = *(const float4*)(in + (size_t)(r0 + r) * Cc + c0 + cq * 4);
    t[r][cq*4+0] = (_Float16)v.x;
    t[r][cq*4+1] = (_Float16)v.y;
    t[r][cq*4+2] = (_Float16)v.z;
    t[r][cq*4+3] = (_Float16)v.w;
  }
  __syncthreads();
#pragma unroll
  for (int i = 0; i < 4; ++i) {
    int c = rq + i * 16;
    f16x4 o;
    o.x = t[cq*4+0][c];
    o.y = t[cq*4+1][c];
    o.z = t[cq*4+2][c];
    o.w = t[cq*4+3][c];
    *(f16x4*)(out + (size_t)(c0 + c) * R + r0 + cq * 4) = o;
  }
}

// ---------------- GEMM1: qkv = x @ w_qkv (R10-proven config) ------------
// 128x128 tile, BK=64, XOR swizzle (R7), counted-vmcnt depth-1 dbuf (R8),
// V fragment-transposed output (R9). R12/R13 falsified more-streams and
// depth-2 alternatives; this is the local optimum (47.5us measured).
__global__ __launch_bounds__(256) void k_gemm_qkv(const _Float16* __restrict__ A,
                                                  const _Float16* __restrict__ BT,
                                                  _Float16* __restrict__ qh,
                                                  _Float16* __restrict__ kh,
                                                  _Float16* __restrict__ vh,
                                                  unsigned* __restrict__ amax_u) {
  __shared__ __align__(16) _Float16 As[2][128 * 64];
  __shared__ __align__(16) _Float16 Bs[2][128 * 64];
  const int tid = threadIdx.x, lane = tid & 63, wave = tid >> 6;
  const int wm = wave >> 1, wn = wave & 1;
  const int mcol = lane & 15, quad = lane >> 4;
  const int m0 = blockIdx.x * 128, n0 = blockIdx.y * 128;
  const int swa = mcol & 7;
  f32x4 acc[4][4] = {};

  auto stage = [&](int buf, int k0) {           // 8 global_load_lds / thread
#pragma unroll
    for (int r = 0; r < 4; ++r) {
      int s = tid + r * 256;                    // LDS slot (16B), linear dest
      int row = s >> 3, kc = (s & 7) ^ (row & 7);  // pre-swizzled source
      GLOAD_LDS(A  + (size_t)(m0 + row) * 1024 + k0 + kc * 8, &As[buf][s * 8]);
      GLOAD_LDS(BT + (size_t)(n0 + row) * 1024 + k0 + kc * 8, &Bs[buf][s * 8]);
    }
  };
  auto compute = [&](int buf) {
#pragma unroll
    for (int kk = 0; kk < 2; ++kk) {
      f16x8 af[4], bf[4];
#pragma unroll
      for (int tm = 0; tm < 4; ++tm) {
        int row = wm * 64 + tm * 16 + mcol;
        af[tm] = *(const f16x8*)&As[buf][(row * 8 + ((kk * 4 + quad) ^ swa)) * 8];
      }
#pragma unroll
      for (int tn = 0; tn < 4; ++tn) {
        int row = wn * 64 + tn * 16 + mcol;
        bf[tn] = *(const f16x8*)&Bs[buf][(row * 8 + ((kk * 4 + quad) ^ swa)) * 8];
      }
#pragma unroll
      for (int tm = 0; tm < 4; ++tm)
#pragma unroll
        for (int tn = 0; tn < 4; ++tn)
          acc[tm][tn] = __builtin_amdgcn_mfma_f32_16x16x32_f16(af[tm], bf[tn], acc[tm][tn], 0, 0, 0);
    }
  };

  stage(0, 0);
#pragma unroll 1
  for (int t = 0; t < 16; ++t) {
    const int cur = t & 1;
    __builtin_amdgcn_s_barrier();
    if (t + 1 < 16) {
      stage(cur ^ 1, (t + 1) * 64);
      asm volatile("s_waitcnt vmcnt(8)" ::: "memory");
    } else {
      asm volatile("s_waitcnt vmcnt(0)" ::: "memory");
    }
    __builtin_amdgcn_s_barrier();
    __builtin_amdgcn_sched_barrier(0);
    compute(cur);
  }

  const int sec = n0 >> 10;
  if (sec < 2) {
    _Float16* dst = sec ? kh : qh;
    float mxv = 0.f;
#pragma unroll
    for (int tm = 0; tm < 4; ++tm)
#pragma unroll
      for (int tn = 0; tn < 4; ++tn) {
        int rowb = m0 + wm * 64 + tm * 16 + quad * 4;
        int col = n0 + wn * 64 + tn * 16 + mcol;
        int cc = col & 1023, h = cc >> 6, d = cc & 63;
        int b = rowb >> 11, n = rowb & 2047;
        f32x4 a = acc[tm][tn];
        mxv = fmaxf(mxv, fmaxf(fmaxf(fabsf(a[0]), fabsf(a[1])),
                               fmaxf(fabsf(a[2]), fabsf(a[3]))));
        f16x4 o;
        o.x = (_Float16)a[0]; o.y = (_Float16)a[1];
        o.z = (_Float16)a[2]; o.w = (_Float16)a[3];
        *(f16x4*)&dst[(size_t)(b * 16 + h) * 131072 + (size_t)(n >> 5) * 2048 + d * 32 + (n & 31)] = o;
      }
#pragma unroll
    for (int off = 32; off; off >>= 1) mxv = fmaxf(mxv, __shfl_xor(mxv, off));
    if (lane == 0) {
      int head = ((n0 & 1023) >> 6) + wn;
      int plane = (m0 >> 11) * 16 + head;
      atomicMax(&amax_u[sec * 32 + plane], __float_as_uint(mxv));
    }
  } else {
    // V: fragment-transposed layout (R9): slab (d>>4)*512, elem
    // ((n>>3)&3)*128 + (d&15)*8 + (n&7).
#pragma unroll
    for (int tm = 0; tm < 4; ++tm)
#pragma unroll
      for (int tn = 0; tn < 4; ++tn) {
        int rowb = m0 + wm * 64 + tm * 16 + quad * 4;
        int col = n0 + wn * 64 + tn * 16 + mcol;
        int cc = col & 1023, h = cc >> 6, d = cc & 63;
        int b = rowb >> 11, n = rowb & 2047;
        f16x4 o;
        o.x = (_Float16)acc[tm][tn][0];
        o.y = (_Float16)acc[tm][tn][1];
        o.z = (_Float16)acc[tm][tn][2];
        o.w = (_Float16)acc[tm][tn][3];
        size_t e = (size_t)(b * 16 + h) * 131072 + (size_t)(n >> 5) * 2048
                 + (d >> 4) * 512 + ((n >> 3) & 3) * 128 + (d & 15) * 8 + (n & 7);
        *(f16x4*)&vh[e] = o;
      }
  }
}

// ---------------- fp8 e4m3 quantize: K ONLY (R13: Q fused into flash) ----
// K fragment interior: quad*128 + mcol*8 (R9, conflict-free).
__global__ __launch_bounds__(256) void k_quant(const _Float16* __restrict__ kh,
                                               const float* __restrict__ amax,
                                               char* __restrict__ k8) {
  __shared__ ushort T[32][72];   // 144B rows: 16B-aligned reads
  int idx = blockIdx.x;          // 0..2047
  int bh = idx >> 6, chunk = idx & 63;
  const _Float16* src = kh + (size_t)bh * NDH + chunk * 2048;
  float s = 448.f / fmaxf(amax[32 + bh], 1e-12f);
  int t = threadIdx.x;
  f16x8 v = *(const f16x8*)(src + t * 8);
  int d = t >> 2, kk0 = (t & 3) * 8;
#pragma unroll
  for (int j = 0; j < 8; ++j) T[kk0 + j][d] = ((const ushort*)&v)[j];
  __syncthreads();
  int r = t >> 3, d0 = (t & 7) * 8;
  f16x8 row = *(const f16x8*)&T[r][d0];
  float f[8];
#pragma unroll
  for (int j = 0; j < 8; ++j) f[j] = (float)((const _Float16*)&row)[j] * s;
  int lo = 0, hi = 0;
  lo = __builtin_amdgcn_cvt_pk_fp8_f32(f[0], f[1], lo, false);
  lo = __builtin_amdgcn_cvt_pk_fp8_f32(f[2], f[3], lo, true);
  hi = __builtin_amdgcn_cvt_pk_fp8_f32(f[4], f[5], hi, false);
  hi = __builtin_amdgcn_cvt_pk_fp8_f32(f[6], f[7], hi, true);
  int2 o; o.x = lo; o.y = hi;
  int e = (r >> 2) & 1;
  int mc = (r >> 3) * 4 + (r & 3);
  int kb = d0 >> 5, dq = (d0 >> 3) & 3;
  char* dst = k8 + (size_t)bh * NDH + chunk * 2048 + (e * 2 + kb) * 512 + dq * 128 + mc * 8;
  *(int2*)dst = o;
}

// ---------------- flash causal attention (dual q-group, fused Q-quant) ---
// R13: Q quantized in-register from tiled fp16 qh (one-time prologue,
// byte-identical to the old q8 path) -> q8 buffer + quant's Q half gone.
__global__ __launch_bounds__(256) void k_flash(const _Float16* __restrict__ qh,
                                               const char* __restrict__ k8,
                                               const _Float16* __restrict__ vh,
                                               const float* __restrict__ amax,
                                               _Float16* __restrict__ attn) {
  const int bh = blockIdx.x;
  const int tid = threadIdx.x;
  const int wave = tid >> 6, lane = tid & 63;
  const int mcol = lane & 15, quad = lane >> 4;
  const int pr = blockIdx.y * 4 + wave;       // 0..63
  const int ga = 127 - pr, gb = pr;
  const int ta  = 16 - (pr >> 3);             // A-tile count (block-uniform)
  const int ntb = (pr >> 3) + 1;              // B-tile count (block-uniform)

  __shared__ __align__(16) char     Ks[2][8192];
  __shared__ __align__(16) _Float16 Vs[2][8192];

  float sq = 448.f / fmaxf(amax[bh], 1e-12f);
  float sk = 448.f / fmaxf(amax[32 + bh], 1e-12f);
  const float c2 = (1.f / (sq * sk)) * 0.125f * 1.44269504089f;  // > 0

  const size_t pbase = (size_t)bh * NDH;
  const char* kpl = k8 + pbase;
  const _Float16* vpl = vh + pbase;
  const int qrowA = ga * 16 + mcol, qrowB = gb * 16 + mcol;

  // ---- fused Q-quant: reproduce q8 row bytes in-register ----
  auto quantQ = [&](int qrow, long& a0, long& a1) {
    const _Float16* qp = qh + pbase + (size_t)(qrow >> 5) * 2048 + (qrow & 31);
    float f[8];
#pragma unroll
    for (int j = 0; j < 8; ++j) f[j] = (float)qp[(quad * 8 + j) * 32] * sq;
    int lo = 0, hi = 0;
    lo = __builtin_amdgcn_cvt_pk_fp8_f32(f[0], f[1], lo, false);
    lo = __builtin_amdgcn_cvt_pk_fp8_f32(f[2], f[3], lo, true);
    hi = __builtin_amdgcn_cvt_pk_fp8_f32(f[4], f[5], hi, false);
    hi = __builtin_amdgcn_cvt_pk_fp8_f32(f[6], f[7], hi, true);
    a0 = ((long)(unsigned)hi << 32) | (unsigned)lo;
#pragma unroll
    for (int j = 0; j < 8; ++j) f[j] = (float)qp[(32 + quad * 8 + j) * 32] * sq;
    lo = 0; hi = 0;
    lo = __builtin_amdgcn_cvt_pk_fp8_f32(f[0], f[1], lo, false);
    lo = __builtin_amdgcn_cvt_pk_fp8_f32(f[2], f[3], lo, true);
    hi = __builtin_amdgcn_cvt_pk_fp8_f32(f[4], f[5], hi, false);
    hi = __builtin_amdgcn_cvt_pk_fp8_f32(f[6], f[7], hi, true);
    a1 = ((long)(unsigned)hi << 32) | (unsigned)lo;
  };
  long aqA0, aqA1, aqB0, aqB1;
  quantQ(qrowA, aqA0, aqA1);
  quantQ(qrowB, aqB0, aqB1);

  f32x4 OA[4] = {}, OB[4] = {};
  float mA = -3e38f, lA = 0.f, mB = -3e38f, lB = 0.f;
  const int b = bh >> 4, h = bh & 15;
  const int kq = quad * 8;
  const int koff = quad * 128 + mcol * 8;     // bytes into K fragment
  const int voff = quad * 128 + mcol * 8;     // elems into V slab

  auto stage = [&](int buf, int t) {          // 6 global_load_lds / thread
    const char* ks = kpl + (size_t)t * 8192;
    const _Float16* vs = vpl + (size_t)t * 8192;
#pragma unroll
    for (int r = 0; r < 2; ++r)
      GLOAD_LDS(ks + (tid + r * 256) * 16, &Ks[buf][(tid + r * 256) * 16]);
#pragma unroll
    for (int r = 0; r < 4; ++r)
      GLOAD_LDS(vs + (tid + r * 256) * 8, &Vs[buf][(tid + r * 256) * 8]);
  };

  auto softmax = [&](f32x4 (&s)[4][2], bool last, int qrow, int n0,
                     float& m_i, float& l_i, f32x4 (&O)[4], f16x8 (&pb)[4]) {
    if (last) {
#pragma unroll
      for (int p = 0; p < 4; ++p)
#pragma unroll
        for (int e = 0; e < 2; ++e)
#pragma unroll
          for (int r = 0; r < 4; ++r) {
            int key = n0 + p * 32 + kq + e * 4 + r;
            s[p][e][r] = (key <= qrow) ? s[p][e][r] : -3e38f;
          }
    }
    float fm[8];
#pragma unroll
    for (int p = 0; p < 4; ++p)
#pragma unroll
      for (int e = 0; e < 2; ++e) {
        f32x4 v = s[p][e];
        fm[p * 2 + e] = fmaxf(fmaxf(v[0], v[1]), fmaxf(v[2], v[3]));
      }
    float mx = fmaxf(fmaxf(fmaxf(fm[0], fm[1]), fmaxf(fm[2], fm[3])),
                     fmaxf(fmaxf(fm[4], fm[5]), fmaxf(fm[6], fm[7])));
    mx = fmaxf(mx, m_i);
    mx = fmaxf(mx, __shfl_xor(mx, 16));
    mx = fmaxf(mx, __shfl_xor(mx, 32));
    float alpha = __builtin_amdgcn_exp2f((m_i - mx) * c2);
    m_i = mx;
    const float nh = -mx * c2;
    float fs[8];
#pragma unroll
    for (int p = 0; p < 4; ++p)
#pragma unroll
      for (int e = 0; e < 2; ++e) {
        float p0 = __builtin_amdgcn_exp2f(fmaf(s[p][e][0], c2, nh));
        float p1 = __builtin_amdgcn_exp2f(fmaf(s[p][e][1], c2, nh));
        float p2 = __builtin_amdgcn_exp2f(fmaf(s[p][e][2], c2, nh));
        float p3 = __builtin_amdgcn_exp2f(fmaf(s[p][e][3], c2, nh));
        s[p][e][0] = p0; s[p][e][1] = p1; s[p][e][2] = p2; s[p][e][3] = p3;
        fs[p * 2 + e] = (p0 + p1) + (p2 + p3);
      }
    float sum = ((fs[0] + fs[1]) + (fs[2] + fs[3])) + ((fs[4] + fs[5]) + (fs[6] + fs[7]));
    sum += __shfl_xor(sum, 16);
    sum += __shfl_xor(sum, 32);
    l_i = l_i * alpha + sum;
#pragma unroll
    for (int dt = 0; dt < 4; ++dt)
#pragma unroll
      for (int r = 0; r < 4; ++r)
        O[dt][r] *= alpha;
#pragma unroll
    for (int p = 0; p < 4; ++p) {
      h16x2* pb2 = (h16x2*)&pb[p];
      pb2[0] = __builtin_amdgcn_cvt_pkrtz(s[p][0][0], s[p][0][1]);
      pb2[1] = __builtin_amdgcn_cvt_pkrtz(s[p][0][2], s[p][0][3]);
      pb2[2] = __builtin_amdgcn_cvt_pkrtz(s[p][1][0], s[p][1][1]);
      pb2[3] = __builtin_amdgcn_cvt_pkrtz(s[p][1][2], s[p][1][3]);
    }
  };

  stage(0, 0);
#pragma unroll 1
  for (int t = 0; t < ta; ++t) {
    const int cur = t & 1;
    __builtin_amdgcn_s_barrier();
    if (t + 1 < ta) {
      stage(cur ^ 1, t + 1);
      asm volatile("s_waitcnt vmcnt(6)" ::: "memory");
    } else {
      asm volatile("s_waitcnt vmcnt(0)" ::: "memory");
    }
    __builtin_amdgcn_s_barrier();
    __builtin_amdgcn_sched_barrier(0);

    const bool doB = (t < ntb);
    const int n0 = t * 128;
    f32x4 sA[4][2], sB[4][2];
#pragma unroll
    for (int p = 0; p < 4; ++p) {
      long kf0 = *(const long*)&Ks[cur][(p * 4 + 0) * 512 + koff];
      long kf1 = *(const long*)&Ks[cur][(p * 4 + 1) * 512 + koff];
      long kf2 = *(const long*)&Ks[cur][(p * 4 + 2) * 512 + koff];
      long kf3 = *(const long*)&Ks[cur][(p * 4 + 3) * 512 + koff];
      f32x4 z = {};
      z = __builtin_amdgcn_mfma_f32_16x16x32_fp8_fp8(kf0, aqA0, z, 0, 0, 0);
      z = __builtin_amdgcn_mfma_f32_16x16x32_fp8_fp8(kf1, aqA1, z, 0, 0, 0);
      sA[p][0] = z;
      z = (f32x4){};
      z = __builtin_amdgcn_mfma_f32_16x16x32_fp8_fp8(kf2, aqA0, z, 0, 0, 0);
      z = __builtin_amdgcn_mfma_f32_16x16x32_fp8_fp8(kf3, aqA1, z, 0, 0, 0);
      sA[p][1] = z;
      if (doB) {
        z = (f32x4){};
        z = __builtin_amdgcn_mfma_f32_16x16x32_fp8_fp8(kf0, aqB0, z, 0, 0, 0);
        z = __builtin_amdgcn_mfma_f32_16x16x32_fp8_fp8(kf1, aqB1, z, 0, 0, 0);
        sB[p][0] = z;
        z = (f32x4){};
        z = __builtin_amdgcn_mfma_f32_16x16x32_fp8_fp8(kf2, aqB0, z, 0, 0, 0);
        z = __builtin_amdgcn_mfma_f32_16x16x32_fp8_fp8(kf3, aqB1, z, 0, 0, 0);
        sB[p][1] = z;
      }
    }
    f16x8 pbA[4], pbB[4];
    softmax(sA, t == ta - 1, qrowA, n0, mA, lA, OA, pbA);
    if (doB) softmax(sB, t == ntb - 1, qrowB, n0, mB, lB, OB, pbB);
#pragma unroll
    for (int p = 0; p < 4; ++p) {
      f16x8 va0 = *(const f16x8*)&Vs[cur][p * 2048 + 0 * 512 + voff];
      f16x8 va1 = *(const f16x8*)&Vs[cur][p * 2048 + 1 * 512 + voff];
      f16x8 va2 = *(const f16x8*)&Vs[cur][p * 2048 + 2 * 512 + voff];
      f16x8 va3 = *(const f16x8*)&Vs[cur][p * 2048 + 3 * 512 + voff];
      OA[0] = __builtin_amdgcn_mfma_f32_16x16x32_f16(va0, pbA[p], OA[0], 0, 0, 0);
      OA[1] = __builtin_amdgcn_mfma_f32_16x16x32_f16(va1, pbA[p], OA[1], 0, 0, 0);
      OA[2] = __builtin_amdgcn_mfma_f32_16x16x32_f16(va2, pbA[p], OA[2], 0, 0, 0);
      OA[3] = __builtin_amdgcn_mfma_f32_16x16x32_f16(va3, pbA[p], OA[3], 0, 0, 0);
      if (doB) {
        OB[0] = __builtin_amdgcn_mfma_f32_16x16x32_f16(va0, pbB[p], OB[0], 0, 0, 0);
        OB[1] = __builtin_amdgcn_mfma_f32_16x16x32_f16(va1, pbB[p], OB[1], 0, 0, 0);
        OB[2] = __builtin_amdgcn_mfma_f32_16x16x32_f16(va2, pbB[p], OB[2], 0, 0, 0);
        OB[3] = __builtin_amdgcn_mfma_f32_16x16x32_f16(va3, pbB[p], OB[3], 0, 0, 0);
      }
    }
  }

  {
    float rl = __builtin_amdgcn_rcpf(lA);
    _Float16* op = attn + ((size_t)b * 2048 + qrowA) * 1024 + h * 64;
#pragma unroll
    for (int dt = 0; dt < 4; ++dt) {
      f16x4 o;
      o.x = (_Float16)(OA[dt][0] * rl);
      o.y = (_Float16)(OA[dt][1] * rl);
      o.z = (_Float16)(OA[dt][2] * rl);
      o.w = (_Float16)(OA[dt][3] * rl);
      *(f16x4*)(op + dt * 16 + quad * 4) = o;
    }
  }
  {
    float rl = __builtin_amdgcn_rcpf(lB);
    _Float16* op = attn + ((size_t)b * 2048 + qrowB) * 1024 + h * 64;
#pragma unroll
    for (int dt = 0; dt < 4; ++dt) {
      f16x4 o;
      o.x = (_Float16)(OB[dt][0] * rl);
      o.y = (_Float16)(OB[dt][1] * rl);
      o.z = (_Float16)(OB[dt][2] * rl);
      o.w = (_Float16)(OB[dt][3] * rl);
      *(f16x4*)(op + dt * 16 + quad * 4) = o;
    }
  }
}

// ---------------- GEMM2: out = attn @ w_proj + b (R10 128^2 config) ------
__global__ __launch_bounds__(256) void k_gemm_out(const _Float16* __restrict__ A,
                                                  const _Float16* __restrict__ BT,
                                                  const float* __restrict__ bias,
                                                  float* __restrict__ out) {
  __shared__ __align__(16) _Float16 As[2][128 * 64];
  __shared__ __align__(16) _Float16 Bs[2][128 * 64];
  const int tid = threadIdx.x, lane = tid & 63, wave = tid >> 6;
  const int wm = wave >> 1, wn = wave & 1;
  const int mcol = lane & 15, quad = lane >> 4;
  const int m0 = blockIdx.x * 128, n0 = blockIdx.y * 128;
  const int swa = mcol & 7;
  f32x4 acc[4][4] = {};

  auto stage = [&](int buf, int k0) {
#pragma unroll
    for (int r = 0; r < 4; ++r) {
      int s = tid + r * 256;
      int row = s >> 3, kc = (s & 7) ^ (row & 7);
      GLOAD_LDS(A  + (size_t)(m0 + row) * 1024 + k0 + kc * 8, &As[buf][s * 8]);
      GLOAD_LDS(BT + (size_t)(n0 + row) * 1024 + k0 + kc * 8, &Bs[buf][s * 8]);
    }
  };
  auto compute = [&](int buf) {
#pragma unroll
    for (int kk = 0; kk < 2; ++kk) {
      f16x8 af[4], bf[4];
#pragma unroll
      for (int tm = 0; tm < 4; ++tm) {
        int row = wm * 64 + tm * 16 + mcol;
        af[tm] = *(const f16x8*)&As[buf][(row * 8 + ((kk * 4 + quad) ^ swa)) * 8];
      }
#pragma unroll
      for (int tn = 0; tn < 4; ++tn) {
        int row = wn * 64 + tn * 16 + mcol;
        bf[tn] = *(const f16x8*)&Bs[buf][(row * 8 + ((kk * 4 + quad) ^ swa)) * 8];
      }
#pragma unroll
      for (int tm = 0; tm < 4; ++tm)
#pragma unroll
        for (int tn = 0; tn < 4; ++tn)
          acc[tm][tn] = __builtin_amdgcn_mfma_f32_16x16x32_f16(af[tm], bf[tn], acc[tm][tn], 0, 0, 0);
    }
  };

  stage(0, 0);
#pragma unroll 1
  for (int t = 0; t < 16; ++t) {
    const int cur = t & 1;
    __builtin_amdgcn_s_barrier();
    if (t + 1 < 16) {
      stage(cur ^ 1, (t + 1) * 64);
      asm volatile("s_waitcnt vmcnt(8)" ::: "memory");
    } else {
      asm volatile("s_waitcnt vmcnt(0)" ::: "memory");
    }
    __builtin_amdgcn_s_barrier();
    __builtin_amdgcn_sched_barrier(0);
    compute(cur);
  }

#pragma unroll
  for (int tm = 0; tm < 4; ++tm)
#pragma unroll
    for (int tn = 0; tn < 4; ++tn)
#pragma unroll
      for (int reg = 0; reg < 4; ++reg) {
        int row = m0 + wm * 64 + tm * 16 + quad * 4 + reg;
        int col = n0 + wn * 64 + tn * 16 + mcol;
        out[(size_t)row * 1024 + col] = acc[tm][tn][reg] + bias[col];
      }
}

extern "C" void kernel_launch(void* const* d_in, const int* in_sizes, int n_in,
                              void* d_out, int out_size, void* d_ws, size_t ws_size,
                              hipStream_t stream) {
  const float* x      = (const float*)d_in[0];
  const float* w_qkv  = (const float*)d_in[1];
  const float* w_proj = (const float*)d_in[2];
  const float* b_proj = (const float*)d_in[3];
  float* out = (float*)d_out;

  char* ws = (char*)d_ws;
  _Float16* xh   = (_Float16*)ws; ws += (size_t)M1 * C_ * 2;
  _Float16* whT  = (_Float16*)ws; ws += (size_t)3 * C_ * C_ * 2;
  _Float16* wpT  = (_Float16*)ws; ws += (size_t)C_ * C_ * 2;
  _Float16* qh   = (_Float16*)ws; ws += (size_t)BH_ * NDH * 2;
  _Float16* kh   = (_Float16*)ws; ws += (size_t)BH_ * NDH * 2;
  _Float16* vh   = (_Float16*)ws; ws += (size_t)BH_ * NDH * 2;
  char*     k8   = (char*)ws;     ws += (size_t)BH_ * NDH;
  _Float16* attn = (_Float16*)ws; ws += (size_t)M1 * C_ * 2;
  float*    amx  = (float*)ws;    ws += 256;

  k_prep<<<5120, 256, 0, stream>>>(x, xh, w_qkv, w_proj, whT, wpT, (unsigned*)amx);
  k_gemm_qkv<<<dim3(M1 / 128, 3 * C_ / 128), 256, 0, stream>>>(xh, whT, qh, kh, vh, (unsigned*)amx);
  k_quant<<<2048, 256, 0, stream>>>(kh, amx, k8);
  k_flash<<<dim3(32, 16), 256, 0, stream>>>(qh, k8, vh, amx, attn);
  k_gemm_out<<<dim3(M1 / 128, C_ / 128), 256, 0, stream>>>(attn, wpT, b_proj, out);
}